// Round 6
// baseline (8989.115 us; speedup 1.0000x reference)
//
#include <hip/hip_runtime.h>

typedef __attribute__((ext_vector_type(8))) short short8;
typedef __attribute__((ext_vector_type(4))) float f32x4;
typedef unsigned short us;

#define OSTEP (256*1408)

// ---- ws layout (ushort elems from base) ----
#define OFF_WIH  ((size_t)0)
#define OFF_WHH  ((size_t)3145728)
#define OFF_WP1  ((size_t)6291456)
#define OFF_WQ1  ((size_t)7340032)
#define OFF_WP2  ((size_t)9437184)
#define OFF_WQ2  ((size_t)9568256)
#define OFF_HBF0 ((size_t)9699328)
#define OFF_HBF1 ((size_t)9961472)
#define OFF_EBF  ((size_t)10223616)
#define OFF_P1E  ((size_t)10485760)
#define OFF_Q1E  ((size_t)10747904)
#define F32_BYTE_OFF ((size_t)22020096)   // fp32 region (16B aligned)
// f32 region bytes: [0,16384) = 256 arrival slots (64B each);
//                   [16384,16448) = go flag; qstg at byte 32768 (f32b+8192)

// ---- dynamic LDS layout (bytes) ----
#define L_WAI 0
#define L_WAH 24576
#define L_WB  49152
#define L_WC  73728
#define L_WD  77824
#define L_SCR 79488
#define LDS_TOTAL 129664

__device__ __forceinline__ unsigned short f2bf(float f){
  union { float f; unsigned u; } v; v.f = f;
  unsigned u = v.u;
  u += 0x7fffu + ((u >> 16) & 1u);
  return (unsigned short)(u >> 16);
}
__device__ __forceinline__ float sigf(float x){ return 1.0f/(1.0f+__expf(-x)); }
__device__ __forceinline__ float tanhf_(float x){
  float e = __expf(-2.0f*fabsf(x));
  float t = (1.0f-e)/(1.0f+e);
  return x>=0.f ? t : -t;
}
__device__ __forceinline__ float eluf(float x){ return x>0.f ? x : __expf(x)-1.0f; }
__device__ __forceinline__ float softplusf(float x){ return x>20.f ? x : log1pf(__expf(x)); }
__device__ __forceinline__ short8 ld8(const us* p){ return *(const short8*)p; }

// =====================================================================
// Weight-stationary persistent megakernel (phases identical to R4/R5)
// =====================================================================

__device__ __forceinline__ void phaseA_new(
    char* lds, int blk, int tid, int t,
    const us* __restrict__ ebf, const us* __restrict__ hb, us* __restrict__ hbn,
    const float* __restrict__ b_ih, const float* __restrict__ b_hh,
    const float* __restrict__ hprev, float* __restrict__ out_t,
    const float* __restrict__ obs, us* __restrict__ obsbf)
{
  int w = tid>>6, lane = tid&63;
  int l15 = lane&15, q8 = (lane>>4)*8;
  int xr = (l15&7)<<4;
  const char* wbi = lds + L_WAI + l15*2048;
  const char* wbh = lds + L_WAH + l15*2048;
  const us* paE = ebf + (size_t)(w*32 + l15)*1024 + q8;
  const us* paH = hb  + (size_t)(w*32 + l15)*1024 + q8;
  f32x4 z={0.f,0.f,0.f,0.f}, aI0=z, aI1=z, aH0=z, aH1=z;
  #pragma unroll 4
  for(int kk=0; kk<1024; kk+=32){
    int kb = (kk+q8)*2;
    short8 bI = *(const short8*)(wbi + (kb^xr));
    short8 bH = *(const short8*)(wbh + (kb^xr));
    short8 e0 = ld8(paE+kk), e1 = ld8(paE+16384+kk);
    short8 h0 = ld8(paH+kk), h1 = ld8(paH+16384+kk);
    aI0 = __builtin_amdgcn_mfma_f32_16x16x32_bf16(e0,bI,aI0,0,0,0);
    aI1 = __builtin_amdgcn_mfma_f32_16x16x32_bf16(e1,bI,aI1,0,0,0);
    aH0 = __builtin_amdgcn_mfma_f32_16x16x32_bf16(h0,bH,aH0,0,0,0);
    aH1 = __builtin_amdgcn_mfma_f32_16x16x32_bf16(h1,bH,aH1,0,0,0);
  }
  float* Gih = (float*)(lds + L_SCR);
  float* Ghh = Gih + 16*257;
  int rr = (lane>>4)*4;
  #pragma unroll
  for(int v=0; v<4; v++){
    Gih[l15*257 + w*32 + rr + v]      = aI0[v];
    Gih[l15*257 + w*32 + 16 + rr + v] = aI1[v];
    Ghh[l15*257 + w*32 + rr + v]      = aH0[v];
    Ghh[l15*257 + w*32 + 16 + rr + v] = aH1[v];
  }
  {
    const float* src = obs + ((size_t)(blk*64) + (t+1))*1024;
    us* dst = obsbf + (size_t)blk*1024;
    for(int i=tid;i<1024;i+=512) dst[i] = f2bf(src[i]);
  }
  __syncthreads();
  for(int i=tid;i<1024;i+=512){
    int di=i>>8, b=i&255; int d=blk*4+di;
    float ir = Gih[(di  )*257 + b] + b_ih[d];
    float iz = Gih[(4+di)*257 + b] + b_ih[1024+d];
    float ia = Gih[(8+di)*257 + b] + b_ih[2048+d];
    float hr = Ghh[(di  )*257 + b] + b_hh[d];
    float hz = Ghh[(4+di)*257 + b] + b_hh[1024+d];
    float ha = Ghh[(8+di)*257 + b] + b_hh[2048+d];
    float r = sigf(ir+hr), zz = sigf(iz+hz);
    float nn = tanhf_(ia + r*ha);
    float hold = hprev ? hprev[(size_t)b*1408 + d] : 0.f;
    float hnew = (1.f-zz)*nn + zz*hold;
    out_t[(size_t)b*1408 + d] = hnew;
    hbn[(size_t)b*1024 + d] = f2bf(hnew);
  }
}

__device__ __forceinline__ void phaseB_new(
    char* lds, int blk, int tid,
    const us* __restrict__ hbn, const us* __restrict__ obsbf,
    const float* __restrict__ bp1, const float* __restrict__ bq1,
    us* __restrict__ p1e, us* __restrict__ q1e)
{
  int w=tid>>6, lane=tid&63, l15=lane&15, q8=(lane>>4)*8, xr=(l15&7)<<4;
  const char* wb = lds + L_WB + l15*2048;
  const us* paH = hbn   + (size_t)(w*32+l15)*1024 + q8;
  const us* paO = obsbf + (size_t)(w*32+l15)*1024 + q8;
  f32x4 z={0.f,0.f,0.f,0.f}, c10=z,c11=z,c20=z,c21=z;
  #pragma unroll 4
  for(int kk=0;kk<1024;kk+=32){
    int kb=(kk+q8)*2;
    short8 bw = *(const short8*)(wb + (kb^xr));
    c10 = __builtin_amdgcn_mfma_f32_16x16x32_bf16(ld8(paH+kk),       bw, c10,0,0,0);
    c11 = __builtin_amdgcn_mfma_f32_16x16x32_bf16(ld8(paH+16384+kk), bw, c11,0,0,0);
    c20 = __builtin_amdgcn_mfma_f32_16x16x32_bf16(ld8(paO+kk),       bw, c20,0,0,0);
    c21 = __builtin_amdgcn_mfma_f32_16x16x32_bf16(ld8(paO+16384+kk), bw, c21,0,0,0);
  }
  float* G1 = (float*)(lds+L_SCR); float* G2 = G1 + 16*257;
  int rr=(lane>>4)*4;
  #pragma unroll
  for(int v=0;v<4;v++){
    G1[l15*257 + w*32 + rr + v]      = c10[v];
    G1[l15*257 + w*32 + 16 + rr + v] = c11[v];
    G2[l15*257 + w*32 + rr + v]      = c20[v];
    G2[l15*257 + w*32 + 16 + rr + v] = c21[v];
  }
  __syncthreads();
  for(int i=tid;i<1024;i+=512){
    int ci=i>>8, b=i&255; int c=blk*4+ci;
    float p1 = eluf(G1[ci*257+b] + bp1[c]);
    float q1 = eluf(G1[(4+ci)*257+b] + G2[(8+ci)*257+b] + bq1[c]);
    p1e[(size_t)b*1024+c]=f2bf(p1);
    q1e[(size_t)b*1024+c]=f2bf(q1);
  }
}

__device__ __forceinline__ void phaseC_new(
    char* lds, int blk, int tid, int t,
    const us* __restrict__ p1e, const us* __restrict__ q1e,
    const float* __restrict__ bp2, const float* __restrict__ bq2,
    const float* __restrict__ np_, const float* __restrict__ nq_,
    float* __restrict__ out_t, float* __restrict__ qstg)
{
  int w=tid>>6, lane=tid&63, l15=lane&15, q8=(lane>>4)*8, xr=(l15&7)<<4;
  int kind = blk>>7, idx=blk&127, s=idx>>1, bh=idx&1, b0=bh*128;
  const us* A = kind ? q1e : p1e;
  const char* wc = lds + L_WC + l15*2048;
  const us* pa = A + (size_t)(b0 + w*16 + l15)*1024 + q8;
  f32x4 c0={0.f,0.f,0.f,0.f};
  #pragma unroll 4
  for(int kk=0;kk<1024;kk+=32){
    int kb=(kk+q8)*2;
    c0 = __builtin_amdgcn_mfma_f32_16x16x32_bf16(ld8(pa+kk), *(const short8*)(wc+(kb^xr)), c0,0,0,0);
  }
  float* Gc=(float*)(lds+L_SCR);
  int rr=(lane>>4)*4;
  #pragma unroll
  for(int v=0;v<4;v++) Gc[l15*129 + w*16 + rr + v] = c0[v];
  __syncthreads();
  const float* b2 = kind? bq2 : bp2;
  const float* nz = kind? nq_ : np_;
  if(tid<128){
    int b=tid, bg=b0+b;
    float mean = Gc[0*129+b] + b2[s];
    float stdv = softplusf(Gc[1*129+b] + b2[64+s]) + 0.1f;
    float st = mean + stdv * nz[((size_t)t*256+bg)*64 + s];
    float* o = out_t + (size_t)bg*1408 + (kind?1216:1024);
    o[s]=mean; o[64+s]=stdv; o[128+s]=st;
    if(kind) qstg[(size_t)bg*64+s]=st;
  }
}

__device__ __forceinline__ void phaseD_new(
    char* lds, int blk, int tid, int t_out, int t_act,
    const float* __restrict__ qstg, const float* __restrict__ act,
    const float* __restrict__ b_sa, us* __restrict__ ebf)
{
  float* wd  = (float*)(lds + L_WD);
  float* qld = (float*)(lds + L_SCR);     // [128][65]
  float* ald = qld + 128*65;              // [128][33]
  int dl = tid>>7, b = tid&127;
  int d = blk*4 + dl;
  float bias = b_sa[d];
  for(int ch=0; ch<2; ch++){
    int B0 = ch*128;
    if(t_out>=0){
      for(int i=tid;i<8192;i+=512){int bb=i>>6,k=i&63; qld[bb*65+k]=qstg[(size_t)(B0+bb)*64+k];}
    } else {
      for(int i=tid;i<8192;i+=512){int bb=i>>6,k=i&63; qld[bb*65+k]=0.f;}
    }
    for(int i=tid;i<4096;i+=512){int bb=i>>5,k=i&31; ald[bb*33+k]=act[((size_t)(B0+bb)*64 + t_act)*32 + k];}
    __syncthreads();
    float a = bias;
    for(int k=0;k<64;k++) a += qld[b*65+k]*wd[dl*96+k];
    for(int k=0;k<32;k++) a += ald[b*33+k]*wd[dl*96+64+k];
    ebf[(size_t)(B0+b)*1024 + d] = f2bf(eluf(a));
    __syncthreads();
  }
}

__global__ __launch_bounds__(512, 1) void k_mega(
    const float* __restrict__ obs, const float* __restrict__ act,
    const float* __restrict__ np_, const float* __restrict__ nq_,
    const float* __restrict__ wsa, const float* __restrict__ bsa,
    const float* __restrict__ wih, const float* __restrict__ bih,
    const float* __restrict__ whh, const float* __restrict__ bhh,
    const float* __restrict__ wp1, const float* __restrict__ bp1,
    const float* __restrict__ wp2, const float* __restrict__ bp2,
    const float* __restrict__ wq1, const float* __restrict__ bq1,
    const float* __restrict__ wq2, const float* __restrict__ bq2,
    float* __restrict__ out, us* __restrict__ wsb)
{
  extern __shared__ char lds[];
  int blk = blockIdx.x, tid = threadIdx.x;

  us* obsbf = wsb + OFF_WIH;   // reuse (fallback-only region)
  us* hbf0  = wsb + OFF_HBF0;
  us* hbf1  = wsb + OFF_HBF1;
  us* ebf   = wsb + OFF_EBF;
  us* p1e   = wsb + OFF_P1E;
  us* q1e   = wsb + OFF_Q1E;
  float* f32b = (float*)((char*)wsb + F32_BYTE_OFF);
  unsigned* slots = (unsigned*)f32b;        // 256 x 64B arrival slots
  unsigned* go    = (unsigned*)f32b + 4096; // byte 16384: go flag (own line)
  float* qstg = f32b + 8192;                // [256][64] f32 at byte 32768

  unsigned ep = 0;
  // Leader barrier: arrivals are parallel release-stores to per-block slots.
  // Only block 0 polls all slots (relaxed + final acquire pass), then
  // release-stores the go epoch. Others poll the single go line.
  // ~320 poll loads/round chip-wide vs R5's ~65K. Bounded spins throughout.
  #define GBAR() do{ __syncthreads(); ++ep; \
    if(tid==0) \
      __hip_atomic_store(slots + (size_t)blk*16, ep, __ATOMIC_RELEASE, __HIP_MEMORY_SCOPE_AGENT); \
    if(blk==0){ \
      if(tid<64){ \
        const unsigned* s0=slots+(size_t)tid*16; \
        unsigned it=0; int done=0; \
        do{ \
          unsigned a=__hip_atomic_load(s0,       __ATOMIC_RELAXED,__HIP_MEMORY_SCOPE_AGENT); \
          unsigned b=__hip_atomic_load(s0+64*16, __ATOMIC_RELAXED,__HIP_MEMORY_SCOPE_AGENT); \
          unsigned c=__hip_atomic_load(s0+128*16,__ATOMIC_RELAXED,__HIP_MEMORY_SCOPE_AGENT); \
          unsigned d=__hip_atomic_load(s0+192*16,__ATOMIC_RELAXED,__HIP_MEMORY_SCOPE_AGENT); \
          int ok = (a>=ep)&&(b>=ep)&&(c>=ep)&&(d>=ep); \
          done = __all(ok); \
          if(!done) __builtin_amdgcn_s_sleep(1); \
        }while(!done && ++it<400000u); \
        (void)__hip_atomic_load(s0,       __ATOMIC_ACQUIRE,__HIP_MEMORY_SCOPE_AGENT); \
        (void)__hip_atomic_load(s0+64*16, __ATOMIC_ACQUIRE,__HIP_MEMORY_SCOPE_AGENT); \
        (void)__hip_atomic_load(s0+128*16,__ATOMIC_ACQUIRE,__HIP_MEMORY_SCOPE_AGENT); \
        (void)__hip_atomic_load(s0+192*16,__ATOMIC_ACQUIRE,__HIP_MEMORY_SCOPE_AGENT); \
        if(tid==0) \
          __hip_atomic_store(go, ep, __ATOMIC_RELEASE, __HIP_MEMORY_SCOPE_AGENT); \
      } \
    } else if(tid==0){ \
      unsigned it=0; \
      while(__hip_atomic_load(go, __ATOMIC_RELAXED, __HIP_MEMORY_SCOPE_AGENT) < ep \
            && ++it<400000u) __builtin_amdgcn_s_sleep(1); \
      (void)__hip_atomic_load(go, __ATOMIC_ACQUIRE, __HIP_MEMORY_SCOPE_AGENT); \
    } \
    __syncthreads(); }while(0)

  // ---------------- prologue: stage resident weights into LDS ----------------
  for(int i=tid; i<12*512; i+=512){
    int r=i>>9, kp=(i&511)*2;
    int srow = (r>>2)*1024 + blk*4 + (r&3);
    float2 vI = *(const float2*)(wih + (size_t)srow*1024 + kp);
    float2 vH = *(const float2*)(whh + (size_t)srow*1024 + kp);
    unsigned pI = (unsigned)f2bf(vI.x) | ((unsigned)f2bf(vI.y)<<16);
    unsigned pH = (unsigned)f2bf(vH.x) | ((unsigned)f2bf(vH.y)<<16);
    int off = r*2048 + ((kp*2)^((r&7)<<4));
    *(unsigned*)(lds + L_WAI + off) = pI;
    *(unsigned*)(lds + L_WAH + off) = pH;
  }
  for(int i=tid; i<12*512; i+=512){
    int r=i>>9, kp=(i&511)*2;
    const float* src;
    if(r<4)      src = wp1 + (size_t)(blk*4+r)*1024 + kp;
    else if(r<8) src = wq1 + (size_t)(blk*4+r-4)*2048 + kp;
    else         src = wq1 + (size_t)(blk*4+r-8)*2048 + 1024 + kp;
    float2 v = *(const float2*)src;
    unsigned p = (unsigned)f2bf(v.x) | ((unsigned)f2bf(v.y)<<16);
    *(unsigned*)(lds + L_WB + r*2048 + ((kp*2)^((r&7)<<4))) = p;
  }
  {
    int kind=blk>>7, s=(blk&127)>>1;
    const float* W2 = kind? wq2 : wp2;
    for(int i=tid; i<2*512; i+=512){
      int r=i>>9, kp=(i&511)*2;
      float2 v = *(const float2*)(W2 + (size_t)((r?64:0)+s)*1024 + kp);
      unsigned p = (unsigned)f2bf(v.x) | ((unsigned)f2bf(v.y)<<16);
      *(unsigned*)(lds + L_WC + r*2048 + ((kp*2)^((r&7)<<4))) = p;
    }
  }
  for(int i=tid;i<384;i+=512){
    int r=i/96, k=i-r*96;
    ((float*)(lds+L_WD))[r*96+k] = wsa[(size_t)(blk*4+r)*96 + k];
  }
  { unsigned long long* p=(unsigned long long*)hbf0;
    for(int i=tid;i<256;i+=512) p[(size_t)blk*256+i]=0ull; }
  __syncthreads();

  // initial e with s0 = 0 (local: LDS weights + act input only)
  phaseD_new(lds, blk, tid, -1, 0, qstg, act, bsa, ebf);
  GBAR();   // covers ebf + hbf0 writes across blocks

  #pragma unroll 1
  for(int t=0; t<63; t++){
    const us* hb = (t&1) ? hbf1 : hbf0;
    us* hbn      = (t&1) ? hbf0 : hbf1;
    const float* hprev = t ? (out + (size_t)(t-1)*OSTEP) : (const float*)nullptr;
    float* out_t = out + (size_t)t*OSTEP;

    phaseA_new(lds, blk, tid, t, ebf, hb, hbn, bih, bhh, hprev, out_t, obs, obsbf);
    GBAR();
    phaseB_new(lds, blk, tid, hbn, obsbf, bp1, bq1, p1e, q1e);
    GBAR();
    phaseC_new(lds, blk, tid, t, p1e, q1e, bp2, bq2, np_, nq_, out_t, qstg);
    GBAR();
    phaseD_new(lds, blk, tid, t, t+1, qstg, act, bsa, ebf);
    GBAR();
  }
  #undef GBAR
}

// =====================================================================
// Fallback path: the verified 4-kernel pipeline
// =====================================================================

__global__ void k_prep(const float* __restrict__ wih, const float* __restrict__ whh,
                       const float* __restrict__ wp1, const float* __restrict__ wq1,
                       const float* __restrict__ wp2, const float* __restrict__ wq2,
                       us* __restrict__ dst){
  size_t i4 = ((size_t)blockIdx.x*256 + threadIdx.x)*4;
  const size_t total = 9699328;
  if(i4 >= total) return;
  const float* src; size_t off;
  if(i4 < 3145728){ src=wih; off=0; }
  else if(i4 < 6291456){ src=whh; off=3145728; }
  else if(i4 < 7340032){ src=wp1; off=6291456; }
  else if(i4 < 9437184){ src=wq1; off=7340032; }
  else if(i4 < 9568256){ src=wp2; off=9437184; }
  else { src=wq2; off=9568256; }
  size_t j = i4 - off;
  float4 v = *(const float4*)(src + j);
  unsigned long long p = (unsigned long long)f2bf(v.x)
                       | ((unsigned long long)f2bf(v.y) << 16)
                       | ((unsigned long long)f2bf(v.z) << 32)
                       | ((unsigned long long)f2bf(v.w) << 48);
  *(unsigned long long*)(dst + i4) = p;
}

__global__ __launch_bounds__(384) void k_gru(
    const us* __restrict__ e_bf, const us* __restrict__ h_bf,
    const us* __restrict__ wih_bf, const us* __restrict__ whh_bf,
    const float* __restrict__ b_ih, const float* __restrict__ b_hh,
    const float* __restrict__ hprev, int hprev_ld,
    float* __restrict__ out_t, us* __restrict__ hnext_bf)
{
  int bx = blockIdx.x, by = blockIdx.y;
  int tid = threadIdx.x, w = tid >> 6, lane = tid & 63;
  int g = w % 3; bool isI = (w < 3);
  const us* A  = isI ? e_bf  : h_bf;
  const us* Bw = isI ? wih_bf : whh_bf;
  int brow = g*1024 + bx*32;
  int arow = by*32;
  int l15 = lane & 15, q8 = (lane >> 4)*8;

  f32x4 z4 = {0.f,0.f,0.f,0.f};
  f32x4 acc00=z4, acc01=z4, acc10=z4, acc11=z4;

  const us* pa0 = A  + (size_t)(arow + l15)*1024 + q8;
  const us* pa1 = pa0 + 16*1024;
  const us* pb0 = Bw + (size_t)(brow + l15)*1024 + q8;
  const us* pb1 = pb0 + 16*1024;

  #pragma unroll 4
  for(int kk=0; kk<1024; kk+=32){
    short8 a0 = ld8(pa0+kk), a1 = ld8(pa1+kk);
    short8 b0 = ld8(pb0+kk), b1 = ld8(pb1+kk);
    acc00 = __builtin_amdgcn_mfma_f32_16x16x32_bf16(a0,b0,acc00,0,0,0);
    acc01 = __builtin_amdgcn_mfma_f32_16x16x32_bf16(a0,b1,acc01,0,0,0);
    acc10 = __builtin_amdgcn_mfma_f32_16x16x32_bf16(a1,b0,acc10,0,0,0);
    acc11 = __builtin_amdgcn_mfma_f32_16x16x32_bf16(a1,b1,acc11,0,0,0);
  }

  __shared__ float sg[6][32][33];
  int rr = (lane>>4)*4;
  #pragma unroll
  for(int v=0; v<4; v++){
    sg[w][0 +rr+v][0 +l15] = acc00[v];
    sg[w][0 +rr+v][16+l15] = acc01[v];
    sg[w][16+rr+v][0 +l15] = acc10[v];
    sg[w][16+rr+v][16+l15] = acc11[v];
  }
  __syncthreads();

  for(int i=tid; i<1024; i+=384){
    int m = i>>5, n = i&31;
    int d = bx*32+n, b = by*32+m;
    float ir = sg[0][m][n] + b_ih[d];
    float iz = sg[1][m][n] + b_ih[1024+d];
    float ia = sg[2][m][n] + b_ih[2048+d];
    float hr = sg[3][m][n] + b_hh[d];
    float hz = sg[4][m][n] + b_hh[1024+d];
    float ha = sg[5][m][n] + b_hh[2048+d];
    float r = sigf(ir+hr), zz = sigf(iz+hz);
    float nn = tanhf_(ia + r*ha);
    float hold = hprev[(size_t)b*hprev_ld + d];
    float hnew = (1.f-zz)*nn + zz*hold;
    out_t[(size_t)b*1408 + d] = hnew;
    hnext_bf[(size_t)b*1024 + d] = f2bf(hnew);
  }
}

__global__ __launch_bounds__(256) void k_heads1(
    const us* __restrict__ hnew_bf,
    const float* __restrict__ obs, int tcol,
    const us* __restrict__ wp1_bf, const us* __restrict__ wq1_bf,
    const float* __restrict__ bp1, const float* __restrict__ bq1,
    us* __restrict__ p1e, us* __restrict__ q1e)
{
  int bx = blockIdx.x, by = blockIdx.y;
  bool isQ = (bx >= 32); int nt = bx & 31;
  int tid = threadIdx.x, w = tid>>6, lane = tid&63;
  int mi = w & 1, ni = w >> 1;
  int l15 = lane & 15, q8 = (lane>>4)*8;
  int arowg = by*32 + mi*16 + l15;
  int browg = nt*32 + ni*16 + l15;

  f32x4 acc = {0.f,0.f,0.f,0.f};
  const us* pa = hnew_bf + (size_t)arowg*1024 + q8;

  if(!isQ){
    const us* pb = wp1_bf + (size_t)browg*1024 + q8;
    #pragma unroll 4
    for(int kk=0; kk<1024; kk+=32){
      acc = __builtin_amdgcn_mfma_f32_16x16x32_bf16(ld8(pa+kk), ld8(pb+kk), acc,0,0,0);
    }
  } else {
    const us* pb = wq1_bf + (size_t)browg*2048 + q8;
    #pragma unroll 4
    for(int kk=0; kk<1024; kk+=32){
      acc = __builtin_amdgcn_mfma_f32_16x16x32_bf16(ld8(pa+kk), ld8(pb+kk), acc,0,0,0);
    }
    const float* obsrow = obs + ((size_t)arowg*64 + tcol)*1024 + q8;
    #pragma unroll 4
    for(int kk=0; kk<1024; kk+=32){
      const float4* f = (const float4*)(obsrow + kk);
      float4 x0 = f[0], x1 = f[1];
      short8 a;
      a[0]=(short)f2bf(x0.x); a[1]=(short)f2bf(x0.y); a[2]=(short)f2bf(x0.z); a[3]=(short)f2bf(x0.w);
      a[4]=(short)f2bf(x1.x); a[5]=(short)f2bf(x1.y); a[6]=(short)f2bf(x1.z); a[7]=(short)f2bf(x1.w);
      acc = __builtin_amdgcn_mfma_f32_16x16x32_bf16(a, ld8(pb+1024+kk), acc,0,0,0);
    }
  }

  const float* bias = isQ ? bq1 : bp1;
  us* dst = isQ ? q1e : p1e;
  int col = browg;
  float bv = bias[col];
  #pragma unroll
  for(int v=0; v<4; v++){
    int b = by*32 + mi*16 + (lane>>4)*4 + v;
    float val = eluf(acc[v] + bv);
    dst[(size_t)b*1024 + col] = f2bf(val);
  }
}

__global__ __launch_bounds__(256) void k_heads2(
    const us* __restrict__ p1e, const us* __restrict__ q1e,
    const us* __restrict__ wp2_bf, const us* __restrict__ wq2_bf,
    const float* __restrict__ bp2, const float* __restrict__ bq2,
    float* __restrict__ pm, float* __restrict__ qm)
{
  int bx = blockIdx.x, by = blockIdx.y;
  int col0 = bx*32; bool isQ = (col0 >= 128); int c0 = col0 & 127;
  int tid = threadIdx.x, w = tid>>6, lane = tid&63;
  int mi = w & 1, ni = w >> 1;
  int l15 = lane & 15, q8 = (lane>>4)*8;
  const us* A  = isQ ? q1e : p1e;
  const us* Bw = isQ ? wq2_bf : wp2_bf;
  const float* bias = isQ ? bq2 : bp2;
  float* outb = isQ ? qm : pm;

  int arowg = by*32 + mi*16 + l15;
  int browg = c0 + ni*16 + l15;
  f32x4 acc = {0.f,0.f,0.f,0.f};
  const us* pa = A  + (size_t)arowg*1024 + q8;
  const us* pb = Bw + (size_t)browg*1024 + q8;
  #pragma unroll 4
  for(int kk=0; kk<1024; kk+=32){
    acc = __builtin_amdgcn_mfma_f32_16x16x32_bf16(ld8(pa+kk), ld8(pb+kk), acc,0,0,0);
  }
  float bv = bias[browg];
  #pragma unroll
  for(int v=0; v<4; v++){
    int b = by*32 + mi*16 + (lane>>4)*4 + v;
    outb[(size_t)b*128 + browg] = acc[v] + bv;
  }
}

__global__ __launch_bounds__(256) void k_sample_e(
    int t_out, int t_act,
    const float* __restrict__ pm, const float* __restrict__ qm,
    const float* __restrict__ noise_p, const float* __restrict__ noise_q,
    const float* __restrict__ act, const float* __restrict__ w_sa,
    const float* __restrict__ b_sa,
    float* __restrict__ out, us* __restrict__ e_bf)
{
  __shared__ float qst[32*64];
  __shared__ float sact[32*32];
  int bx = blockIdx.x, by = blockIdx.y, tid = threadIdx.x;

  if(t_out >= 0){
    float* out_t = out + (size_t)t_out*OSTEP;
    for(int i=tid; i<2048; i+=256){
      int m = i>>6, s = i&63; int b = by*32+m;
      float qmean = qm[(size_t)b*128 + s];
      float qstd  = softplusf(qm[(size_t)b*128 + 64 + s]) + 0.1f;
      float qs = qmean + qstd * noise_q[((size_t)t_out*256 + b)*64 + s];
      qst[m*64+s] = qs;
      if(bx == 0){
        float pmean = pm[(size_t)b*128 + s];
        float pstd  = softplusf(pm[(size_t)b*128 + 64 + s]) + 0.1f;
        float ps = pmean + pstd * noise_p[((size_t)t_out*256 + b)*64 + s];
        float* o = out_t + (size_t)b*1408;
        o[1024+s] = pmean; o[1088+s] = pstd; o[1152+s] = ps;
        o[1216+s] = qmean; o[1280+s] = qstd; o[1344+s] = qs;
      }
    }
  } else {
    for(int i=tid; i<2048; i+=256) qst[i] = 0.f;
  }
  for(int i=tid; i<1024; i+=256){
    int m = i>>5, k = i&31;
    sact[i] = act[((size_t)(by*32+m)*64 + t_act)*32 + k];
  }
  __syncthreads();

  int n = tid & 31, mb = tid >> 5;
  int d = bx*32 + n;
  const float* wrow = w_sa + (size_t)d*96;
  float a0=b_sa[d], a1=a0, a2=a0, a3=a0;
  for(int k=0; k<64; k++){
    float wv = wrow[k];
    a0 += qst[(mb+ 0)*64+k]*wv;
    a1 += qst[(mb+ 8)*64+k]*wv;
    a2 += qst[(mb+16)*64+k]*wv;
    a3 += qst[(mb+24)*64+k]*wv;
  }
  for(int k=0; k<32; k++){
    float wv = wrow[64+k];
    a0 += sact[(mb+ 0)*32+k]*wv;
    a1 += sact[(mb+ 8)*32+k]*wv;
    a2 += sact[(mb+16)*32+k]*wv;
    a3 += sact[(mb+24)*32+k]*wv;
  }
  e_bf[(size_t)(by*32+mb+ 0)*1024 + d] = f2bf(eluf(a0));
  e_bf[(size_t)(by*32+mb+ 8)*1024 + d] = f2bf(eluf(a1));
  e_bf[(size_t)(by*32+mb+16)*1024 + d] = f2bf(eluf(a2));
  e_bf[(size_t)(by*32+mb+24)*1024 + d] = f2bf(eluf(a3));
}

extern "C" void kernel_launch(void* const* d_in, const int* in_sizes, int n_in,
                              void* d_out, int out_size, void* d_ws, size_t ws_size,
                              hipStream_t stream) {
  const float* obs = (const float*)d_in[0];
  const float* act = (const float*)d_in[1];
  const float* np_ = (const float*)d_in[2];
  const float* nq_ = (const float*)d_in[3];
  const float* wsa = (const float*)d_in[4];
  const float* bsa = (const float*)d_in[5];
  const float* wih = (const float*)d_in[6];
  const float* bih = (const float*)d_in[7];
  const float* whh = (const float*)d_in[8];
  const float* bhh = (const float*)d_in[9];
  const float* wp1 = (const float*)d_in[10];
  const float* bp1 = (const float*)d_in[11];
  const float* wp2 = (const float*)d_in[12];
  const float* bp2 = (const float*)d_in[13];
  const float* wq1 = (const float*)d_in[14];
  const float* bq1 = (const float*)d_in[15];
  const float* wq2 = (const float*)d_in[16];
  const float* bq2 = (const float*)d_in[17];
  float* out = (float*)d_out;
  us* wsb = (us*)d_ws;

  // zero barrier slots + go flag (in the h0 hole)
  hipMemsetAsync((char*)d_ws + F32_BYTE_OFF, 0, 16640, stream);

  // ---- primary path: weight-stationary persistent cooperative kernel ----
  static int lds_ok = -1;
  if (lds_ok < 0) {
    hipError_t e = hipFuncSetAttribute((const void*)k_mega,
                     hipFuncAttributeMaxDynamicSharedMemorySize, LDS_TOTAL);
    lds_ok = (e == hipSuccess) ? 1 : 0;
  }
  if (lds_ok == 1) {
    void* args[] = {
      (void*)&obs, (void*)&act, (void*)&np_, (void*)&nq_,
      (void*)&wsa, (void*)&bsa, (void*)&wih, (void*)&bih,
      (void*)&whh, (void*)&bhh, (void*)&wp1, (void*)&bp1,
      (void*)&wp2, (void*)&bp2, (void*)&wq1, (void*)&bq1,
      (void*)&wq2, (void*)&bq2, (void*)&out, (void*)&wsb
    };
    hipError_t err = hipLaunchCooperativeKernel((const void*)k_mega,
                                                dim3(256), dim3(512),
                                                args, LDS_TOTAL, stream);
    if (err == hipSuccess) return;
  }

  // ---- fallback: verified 4-kernel pipeline ----
  us* wihb = wsb + OFF_WIH;
  us* whhb = wsb + OFF_WHH;
  us* wp1b = wsb + OFF_WP1;
  us* wq1b = wsb + OFF_WQ1;
  us* wp2b = wsb + OFF_WP2;
  us* wq2b = wsb + OFF_WQ2;
  us* hbf0 = wsb + OFF_HBF0;
  us* hbf1 = wsb + OFF_HBF1;
  us* ebf  = wsb + OFF_EBF;
  us* p1e  = wsb + OFF_P1E;
  us* q1e  = wsb + OFF_Q1E;
  float* f32b = (float*)((char*)d_ws + F32_BYTE_OFF);
  float* h0 = f32b;
  float* pm = f32b + 262144;
  float* qm = f32b + 262144 + 32768;

  hipMemsetAsync(hbf0, 0, 262144*2, stream);
  hipMemsetAsync(h0, 0, 262144*4, stream);

  k_prep<<<9472, 256, 0, stream>>>(wih, whh, wp1, wq1, wp2, wq2, wsb);
  k_sample_e<<<dim3(32,8), 256, 0, stream>>>(-1, 0, pm, qm, np_, nq_, act, wsa, bsa, out, ebf);

  for(int t=0; t<63; t++){
    const us* hb = (t&1) ? hbf1 : hbf0;
    us* hbn      = (t&1) ? hbf0 : hbf1;
    const float* hprev = t ? (out + (size_t)(t-1)*OSTEP) : h0;
    int hld = t ? 1408 : 1024;
    k_gru<<<dim3(32,8), 384, 0, stream>>>(ebf, hb, wihb, whhb, bih, bhh,
                                          hprev, hld, out + (size_t)t*OSTEP, hbn);
    k_heads1<<<dim3(64,8), 256, 0, stream>>>(hbn, obs, t+1, wp1b, wq1b, bp1, bq1, p1e, q1e);
    k_heads2<<<dim3(8,8), 256, 0, stream>>>(p1e, q1e, wp2b, wq2b, bp2, bq2, pm, qm);
    k_sample_e<<<dim3(32,8), 256, 0, stream>>>(t, t+1, pm, qm, np_, nq_, act, wsa, bsa, out, ebf);
  }
}

// Round 7
// 6226.074 us; speedup vs baseline: 1.4438x; 1.4438x over previous
//
#include <hip/hip_runtime.h>

typedef __attribute__((ext_vector_type(8))) short short8;
typedef __attribute__((ext_vector_type(4))) float f32x4;
typedef unsigned short us;

#define OSTEP (256*1408)

// ---- ws layout (ushort elems from base) ----
#define OFF_WIH  ((size_t)0)
#define OFF_WHH  ((size_t)3145728)
#define OFF_WP1  ((size_t)6291456)
#define OFF_WQ1  ((size_t)7340032)
#define OFF_WP2  ((size_t)9437184)
#define OFF_WQ2  ((size_t)9568256)
#define OFF_HBF0 ((size_t)9699328)
#define OFF_HBF1 ((size_t)9961472)
#define OFF_EBF  ((size_t)10223616)
#define OFF_P1E  ((size_t)10485760)
#define OFF_Q1E  ((size_t)10747904)
#define F32_BYTE_OFF ((size_t)22020096)   // fp32 region: h0, pm, qm

__device__ __forceinline__ unsigned short f2bf(float f){
  union { float f; unsigned u; } v; v.f = f;
  unsigned u = v.u;
  u += 0x7fffu + ((u >> 16) & 1u);
  return (unsigned short)(u >> 16);
}
__device__ __forceinline__ float sigf(float x){ return 1.0f/(1.0f+__expf(-x)); }
__device__ __forceinline__ float tanhf_(float x){
  float e = __expf(-2.0f*fabsf(x));
  float t = (1.0f-e)/(1.0f+e);
  return x>=0.f ? t : -t;
}
__device__ __forceinline__ float eluf(float x){ return x>0.f ? x : __expf(x)-1.0f; }
__device__ __forceinline__ float softplusf(float x){ return x>20.f ? x : log1pf(__expf(x)); }
__device__ __forceinline__ short8 ld8(const us* p){ return *(const short8*)p; }

// ---------------- prep: fp32 -> bf16 weight conversion ----------------
__global__ void k_prep(const float* __restrict__ wih, const float* __restrict__ whh,
                       const float* __restrict__ wp1, const float* __restrict__ wq1,
                       const float* __restrict__ wp2, const float* __restrict__ wq2,
                       us* __restrict__ dst){
  size_t i4 = ((size_t)blockIdx.x*256 + threadIdx.x)*4;
  const size_t total = 9699328;
  if(i4 >= total) return;
  const float* src; size_t off;
  if(i4 < 3145728){ src=wih; off=0; }
  else if(i4 < 6291456){ src=whh; off=3145728; }
  else if(i4 < 7340032){ src=wp1; off=6291456; }
  else if(i4 < 9437184){ src=wq1; off=7340032; }
  else if(i4 < 9568256){ src=wp2; off=9437184; }
  else { src=wq2; off=9568256; }
  size_t j = i4 - off;
  float4 v = *(const float4*)(src + j);
  unsigned long long p = (unsigned long long)f2bf(v.x)
                       | ((unsigned long long)f2bf(v.y) << 16)
                       | ((unsigned long long)f2bf(v.z) << 32)
                       | ((unsigned long long)f2bf(v.w) << 48);
  *(unsigned long long*)(dst + i4) = p;
}

// ---------------- K1: GRU ----------------
// grid(32, 16): x = d-tile (32 cols), y = b-tile (16 rows). block = 384 (6 waves).
// 512 blocks -> 2 blocks/CU -> 12 waves/CU (was 6): 2x latency hiding.
__global__ __launch_bounds__(384) void k_gru(
    const us* __restrict__ e_bf, const us* __restrict__ h_bf,
    const us* __restrict__ wih_bf, const us* __restrict__ whh_bf,
    const float* __restrict__ b_ih, const float* __restrict__ b_hh,
    const float* __restrict__ hprev, int hprev_ld,
    float* __restrict__ out_t, us* __restrict__ hnext_bf)
{
  int bx = blockIdx.x, by = blockIdx.y;
  int tid = threadIdx.x, w = tid >> 6, lane = tid & 63;
  int g = w % 3; bool isI = (w < 3);
  const us* A  = isI ? e_bf  : h_bf;
  const us* Bw = isI ? wih_bf : whh_bf;
  int brow = g*1024 + bx*32;
  int arow = by*16;
  int l15 = lane & 15, q8 = (lane >> 4)*8;

  f32x4 z4 = {0.f,0.f,0.f,0.f};
  f32x4 acc0=z4, acc1=z4;

  const us* pa0 = A  + (size_t)(arow + l15)*1024 + q8;
  const us* pb0 = Bw + (size_t)(brow + l15)*1024 + q8;
  const us* pb1 = pb0 + 16*1024;

  #pragma unroll 8
  for(int kk=0; kk<1024; kk+=32){
    short8 a0 = ld8(pa0+kk);
    short8 b0 = ld8(pb0+kk), b1 = ld8(pb1+kk);
    acc0 = __builtin_amdgcn_mfma_f32_16x16x32_bf16(a0,b0,acc0,0,0,0);
    acc1 = __builtin_amdgcn_mfma_f32_16x16x32_bf16(a0,b1,acc1,0,0,0);
  }

  __shared__ float sg[6][16][33];
  int rr = (lane>>4)*4;
  #pragma unroll
  for(int v=0; v<4; v++){
    sg[w][rr+v][0 +l15] = acc0[v];
    sg[w][rr+v][16+l15] = acc1[v];
  }
  __syncthreads();

  for(int i=tid; i<512; i+=384){
    int m = i>>5, n = i&31;
    int d = bx*32+n, b = by*16+m;
    float ir = sg[0][m][n] + b_ih[d];
    float iz = sg[1][m][n] + b_ih[1024+d];
    float ia = sg[2][m][n] + b_ih[2048+d];
    float hr = sg[3][m][n] + b_hh[d];
    float hz = sg[4][m][n] + b_hh[1024+d];
    float ha = sg[5][m][n] + b_hh[2048+d];
    float r = sigf(ir+hr), zz = sigf(iz+hz);
    float nn = tanhf_(ia + r*ha);
    float hold = hprev[(size_t)b*hprev_ld + d];
    float hnew = (1.f-zz)*nn + zz*hold;
    out_t[(size_t)b*1408 + d] = hnew;
    hnext_bf[(size_t)b*1024 + d] = f2bf(hnew);
  }
}

// ---------------- K2: p1 = elu(h@Wp1^T+b), q1 = elu([h,obs]@Wq1^T+b) ----------------
// grid(64, 16): x<32 -> p1 tile, x>=32 -> q1 tile; y = 16-batch tile.
// block = 256 (4 waves): wave = (kh = w>>1 K-half) x (ni = w&1 col-subtile).
// 1024 blocks -> 4/CU -> 16 waves/CU; K-split doubles independent load streams.
__global__ __launch_bounds__(256) void k_heads1(
    const us* __restrict__ hnew_bf,
    const float* __restrict__ obs, int tcol,
    const us* __restrict__ wp1_bf, const us* __restrict__ wq1_bf,
    const float* __restrict__ bp1, const float* __restrict__ bq1,
    us* __restrict__ p1e, us* __restrict__ q1e)
{
  int bx = blockIdx.x, by = blockIdx.y;
  bool isQ = (bx >= 32); int nt = bx & 31;
  int tid = threadIdx.x, w = tid>>6, lane = tid&63;
  int ni = w & 1, kh = w >> 1;
  int l15 = lane & 15, q8 = (lane>>4)*8;
  int arowg = by*16 + l15;
  int browg = nt*32 + ni*16 + l15;
  int k0 = kh*512;

  f32x4 acc = {0.f,0.f,0.f,0.f};
  const us* pa = hnew_bf + (size_t)arowg*1024 + q8 + k0;

  if(!isQ){
    const us* pb = wp1_bf + (size_t)browg*1024 + q8 + k0;
    #pragma unroll 8
    for(int kk=0; kk<512; kk+=32){
      acc = __builtin_amdgcn_mfma_f32_16x16x32_bf16(ld8(pa+kk), ld8(pb+kk), acc,0,0,0);
    }
  } else {
    const us* pb = wq1_bf + (size_t)browg*2048 + q8 + k0;
    #pragma unroll 8
    for(int kk=0; kk<512; kk+=32){
      acc = __builtin_amdgcn_mfma_f32_16x16x32_bf16(ld8(pa+kk), ld8(pb+kk), acc,0,0,0);
    }
    const float* obsrow = obs + ((size_t)arowg*64 + tcol)*1024 + q8 + k0;
    const us* pb2 = wq1_bf + (size_t)browg*2048 + 1024 + q8 + k0;
    #pragma unroll 4
    for(int kk=0; kk<512; kk+=32){
      const float4* f = (const float4*)(obsrow + kk);
      float4 x0 = f[0], x1 = f[1];
      short8 a;
      a[0]=(short)f2bf(x0.x); a[1]=(short)f2bf(x0.y); a[2]=(short)f2bf(x0.z); a[3]=(short)f2bf(x0.w);
      a[4]=(short)f2bf(x1.x); a[5]=(short)f2bf(x1.y); a[6]=(short)f2bf(x1.z); a[7]=(short)f2bf(x1.w);
      acc = __builtin_amdgcn_mfma_f32_16x16x32_bf16(a, ld8(pb2+kk), acc,0,0,0);
    }
  }

  __shared__ float sg[4][16][17];
  int rr=(lane>>4)*4;
  #pragma unroll
  for(int v=0;v<4;v++) sg[w][rr+v][l15] = acc[v];
  __syncthreads();

  const float* bias = isQ ? bq1 : bp1;
  us* dst = isQ ? q1e : p1e;
  for(int i=tid; i<512; i+=256){
    int m = i>>5, n = i&31;
    int nni = n>>4, nn = n&15;
    float val = sg[nni][m][nn] + sg[2+nni][m][nn];   // sum K-halves
    int col = nt*32 + n;
    int b = by*16 + m;
    dst[(size_t)b*1024 + col] = f2bf(eluf(val + bias[col]));
  }
}

// ---------------- K3: pm = p1e@Wp2^T+bp2 ; qm = q1e@Wq2^T+bq2 ----------------
// grid(8, 16): x = 32-col tile over [pm(128)|qm(128)]; y = 16-batch tile.
// Same wave split as k_heads1: (kh, ni).
__global__ __launch_bounds__(256) void k_heads2(
    const us* __restrict__ p1e, const us* __restrict__ q1e,
    const us* __restrict__ wp2_bf, const us* __restrict__ wq2_bf,
    const float* __restrict__ bp2, const float* __restrict__ bq2,
    float* __restrict__ pm, float* __restrict__ qm)
{
  int bx = blockIdx.x, by = blockIdx.y;
  int col0 = bx*32; bool isQ = (col0 >= 128); int c0 = col0 & 127;
  int tid = threadIdx.x, w = tid>>6, lane = tid&63;
  int ni = w & 1, kh = w >> 1;
  int l15 = lane & 15, q8 = (lane>>4)*8;
  const us* A  = isQ ? q1e : p1e;
  const us* Bw = isQ ? wq2_bf : wp2_bf;
  const float* bias = isQ ? bq2 : bp2;
  float* outb = isQ ? qm : pm;

  int arowg = by*16 + l15;
  int browg = c0 + ni*16 + l15;
  int k0 = kh*512;
  f32x4 acc = {0.f,0.f,0.f,0.f};
  const us* pa = A  + (size_t)arowg*1024 + q8 + k0;
  const us* pb = Bw + (size_t)browg*1024 + q8 + k0;
  #pragma unroll 8
  for(int kk=0; kk<512; kk+=32){
    acc = __builtin_amdgcn_mfma_f32_16x16x32_bf16(ld8(pa+kk), ld8(pb+kk), acc,0,0,0);
  }

  __shared__ float sg[4][16][17];
  int rr=(lane>>4)*4;
  #pragma unroll
  for(int v=0;v<4;v++) sg[w][rr+v][l15] = acc[v];
  __syncthreads();

  for(int i=tid; i<512; i+=256){
    int m = i>>5, n = i&31;
    int nni = n>>4, nn = n&15;
    float val = sg[nni][m][nn] + sg[2+nni][m][nn];
    int col = c0 + n;
    int b = by*16 + m;
    outb[(size_t)b*128 + col] = val + bias[col];
  }
}

// ---------------- K4: sampling + output writes + e_next ----------------
// grid(32, 8): x = d-tile of e_next, y = b-tile. block 256.  (unchanged)
__global__ __launch_bounds__(256) void k_sample_e(
    int t_out, int t_act,
    const float* __restrict__ pm, const float* __restrict__ qm,
    const float* __restrict__ noise_p, const float* __restrict__ noise_q,
    const float* __restrict__ act, const float* __restrict__ w_sa,
    const float* __restrict__ b_sa,
    float* __restrict__ out, us* __restrict__ e_bf)
{
  __shared__ float qst[32*64];
  __shared__ float sact[32*32];
  int bx = blockIdx.x, by = blockIdx.y, tid = threadIdx.x;

  if(t_out >= 0){
    float* out_t = out + (size_t)t_out*OSTEP;
    for(int i=tid; i<2048; i+=256){
      int m = i>>6, s = i&63; int b = by*32+m;
      float qmean = qm[(size_t)b*128 + s];
      float qstd  = softplusf(qm[(size_t)b*128 + 64 + s]) + 0.1f;
      float qs = qmean + qstd * noise_q[((size_t)t_out*256 + b)*64 + s];
      qst[m*64+s] = qs;
      if(bx == 0){
        float pmean = pm[(size_t)b*128 + s];
        float pstd  = softplusf(pm[(size_t)b*128 + 64 + s]) + 0.1f;
        float ps = pmean + pstd * noise_p[((size_t)t_out*256 + b)*64 + s];
        float* o = out_t + (size_t)b*1408;
        o[1024+s] = pmean; o[1088+s] = pstd; o[1152+s] = ps;
        o[1216+s] = qmean; o[1280+s] = qstd; o[1344+s] = qs;
      }
    }
  } else {
    for(int i=tid; i<2048; i+=256) qst[i] = 0.f;
  }
  for(int i=tid; i<1024; i+=256){
    int m = i>>5, k = i&31;
    sact[i] = act[((size_t)(by*32+m)*64 + t_act)*32 + k];
  }
  __syncthreads();

  int n = tid & 31, mb = tid >> 5;
  int d = bx*32 + n;
  const float* wrow = w_sa + (size_t)d*96;
  float a0=b_sa[d], a1=a0, a2=a0, a3=a0;
  for(int k=0; k<64; k++){
    float wv = wrow[k];
    a0 += qst[(mb+ 0)*64+k]*wv;
    a1 += qst[(mb+ 8)*64+k]*wv;
    a2 += qst[(mb+16)*64+k]*wv;
    a3 += qst[(mb+24)*64+k]*wv;
  }
  for(int k=0; k<32; k++){
    float wv = wrow[64+k];
    a0 += sact[(mb+ 0)*32+k]*wv;
    a1 += sact[(mb+ 8)*32+k]*wv;
    a2 += sact[(mb+16)*32+k]*wv;
    a3 += sact[(mb+24)*32+k]*wv;
  }
  e_bf[(size_t)(by*32+mb+ 0)*1024 + d] = f2bf(eluf(a0));
  e_bf[(size_t)(by*32+mb+ 8)*1024 + d] = f2bf(eluf(a1));
  e_bf[(size_t)(by*32+mb+16)*1024 + d] = f2bf(eluf(a2));
  e_bf[(size_t)(by*32+mb+24)*1024 + d] = f2bf(eluf(a3));
}

extern "C" void kernel_launch(void* const* d_in, const int* in_sizes, int n_in,
                              void* d_out, int out_size, void* d_ws, size_t ws_size,
                              hipStream_t stream) {
  const float* obs = (const float*)d_in[0];
  const float* act = (const float*)d_in[1];
  const float* np_ = (const float*)d_in[2];
  const float* nq_ = (const float*)d_in[3];
  const float* wsa = (const float*)d_in[4];
  const float* bsa = (const float*)d_in[5];
  const float* wih = (const float*)d_in[6];
  const float* bih = (const float*)d_in[7];
  const float* whh = (const float*)d_in[8];
  const float* bhh = (const float*)d_in[9];
  const float* wp1 = (const float*)d_in[10];
  const float* bp1 = (const float*)d_in[11];
  const float* wp2 = (const float*)d_in[12];
  const float* bp2 = (const float*)d_in[13];
  const float* wq1 = (const float*)d_in[14];
  const float* bq1 = (const float*)d_in[15];
  const float* wq2 = (const float*)d_in[16];
  const float* bq2 = (const float*)d_in[17];
  float* out = (float*)d_out;
  us* wsb = (us*)d_ws;

  us* wihb = wsb + OFF_WIH;
  us* whhb = wsb + OFF_WHH;
  us* wp1b = wsb + OFF_WP1;
  us* wq1b = wsb + OFF_WQ1;
  us* wp2b = wsb + OFF_WP2;
  us* wq2b = wsb + OFF_WQ2;
  us* hbf0 = wsb + OFF_HBF0;
  us* hbf1 = wsb + OFF_HBF1;
  us* ebf  = wsb + OFF_EBF;
  us* p1e  = wsb + OFF_P1E;
  us* q1e  = wsb + OFF_Q1E;
  float* f32b = (float*)((char*)d_ws + F32_BYTE_OFF);
  float* h0 = f32b;
  float* pm = f32b + 262144;
  float* qm = f32b + 262144 + 32768;

  hipMemsetAsync(hbf0, 0, 262144*2, stream);
  hipMemsetAsync(h0, 0, 262144*4, stream);

  k_prep<<<9472, 256, 0, stream>>>(wih, whh, wp1, wq1, wp2, wq2, wsb);

  // e_0 with s0 = 0
  k_sample_e<<<dim3(32,8), 256, 0, stream>>>(-1, 0, pm, qm, np_, nq_, act, wsa, bsa, out, ebf);

  for(int t=0; t<63; t++){
    const us* hb = (t&1) ? hbf1 : hbf0;
    us* hbn      = (t&1) ? hbf0 : hbf1;
    const float* hprev = t ? (out + (size_t)(t-1)*OSTEP) : h0;
    int hld = t ? 1408 : 1024;
    k_gru<<<dim3(32,16), 384, 0, stream>>>(ebf, hb, wihb, whhb, bih, bhh,
                                           hprev, hld, out + (size_t)t*OSTEP, hbn);
    k_heads1<<<dim3(64,16), 256, 0, stream>>>(hbn, obs, t+1, wp1b, wq1b, bp1, bq1, p1e, q1e);
    k_heads2<<<dim3(8,16), 256, 0, stream>>>(p1e, q1e, wp2b, wq2b, bp2, bq2, pm, qm);
    k_sample_e<<<dim3(32,8), 256, 0, stream>>>(t, t+1, pm, qm, np_, nq_, act, wsa, bsa, out, ebf);
  }
}